// Round 1
// baseline (507.108 us; speedup 1.0000x reference)
//
#include <hip/hip_runtime.h>
#include <stdint.h>

typedef unsigned short u16;
typedef __bf16 bf16x8 __attribute__((ext_vector_type(8)));
typedef float f32x4 __attribute__((ext_vector_type(4)));
typedef unsigned int u32x4 __attribute__((ext_vector_type(4)));

#define S_LEN 2048
#define NHEAD 16

__device__ __forceinline__ float bf2f(u16 u) {
  union { unsigned int i; float f; } v; v.i = ((unsigned int)u) << 16; return v.f;
}
__device__ __forceinline__ u16 f2bf(float f) {
  union { float f; unsigned int i; } v; v.f = f;
  unsigned int x = v.i;
  return (u16)((x + 0x7fffu + ((x >> 16) & 1u)) >> 16);
}

// ---------------- cast kernels ----------------
__global__ __launch_bounds__(256) void cast_f32_bf16(const float* __restrict__ src,
                                                     u16* __restrict__ dst, long n4) {
  long i = (long)blockIdx.x * 256 + threadIdx.x;
  if (i >= n4) return;
  float4 v = ((const float4*)src)[i];
  unsigned long long r = (unsigned long long)f2bf(v.x)
                       | ((unsigned long long)f2bf(v.y) << 16)
                       | ((unsigned long long)f2bf(v.z) << 32)
                       | ((unsigned long long)f2bf(v.w) << 48);
  ((unsigned long long*)dst)[i] = r;
}

// pad rows >= src_rows with zeros (wkv_a: 576 -> 640 rows)
__global__ __launch_bounds__(256) void cast_pad(const float* __restrict__ src,
                                                u16* __restrict__ dst, int src_rows,
                                                long n4, int cols) {
  long i = (long)blockIdx.x * 256 + threadIdx.x;
  if (i >= n4) return;
  long e0 = i * 4;
  int row = (int)(e0 / cols);
  unsigned long long r = 0;
  if (row < src_rows) {
    float4 v = *(const float4*)(src + e0);
    r = (unsigned long long)f2bf(v.x)
      | ((unsigned long long)f2bf(v.y) << 16)
      | ((unsigned long long)f2bf(v.z) << 32)
      | ((unsigned long long)f2bf(v.w) << 48);
  }
  ((unsigned long long*)dst)[i] = r;
}

// ---------------- NT GEMM: C[M][N] = A[M][K] * B[N][K]^T ----------------
// 128x128 tile, BK=64, 4 waves (2x2 of 64x64), XOR chunk swizzle in LDS.
template <typename OUT>
__global__ __launch_bounds__(256) void gemm_nt(const u16* __restrict__ A, int lda,
                                               const u16* __restrict__ B, int ldb,
                                               OUT* __restrict__ C, int ldc, int K) {
  __shared__ u16 As[128 * 64];
  __shared__ u16 Bs[128 * 64];
  const int tid = threadIdx.x;
  const int lane = tid & 63, wid = tid >> 6;
  const int l15 = lane & 15, l4 = lane >> 4;
  const int wr = wid >> 1, wc = wid & 1;
  const long bm = (long)blockIdx.y * 128;
  const long bn = (long)blockIdx.x * 128;

  f32x4 acc[4][4] = {};

  for (int k0 = 0; k0 < K; k0 += 64) {
    u32x4 ra[4], rb[4];
#pragma unroll
    for (int i = 0; i < 4; ++i) {
      int flat = i * 256 + tid;
      int row = flat >> 3, c = flat & 7;
      ra[i] = *(const u32x4*)(A + (bm + row) * lda + k0 + c * 8);
      rb[i] = *(const u32x4*)(B + (bn + row) * ldb + k0 + c * 8);
    }
    __syncthreads();
#pragma unroll
    for (int i = 0; i < 4; ++i) {
      int flat = i * 256 + tid;
      int row = flat >> 3, c = flat & 7;
      int sc = c ^ (row & 7);
      *(u32x4*)(&As[row * 64 + sc * 8]) = ra[i];
      *(u32x4*)(&Bs[row * 64 + sc * 8]) = rb[i];
    }
    __syncthreads();
#pragma unroll
    for (int kk = 0; kk < 2; ++kk) {
      bf16x8 af[4], bfr[4];
#pragma unroll
      for (int m = 0; m < 4; ++m) {
        int row = wr * 64 + m * 16 + l15;
        int c = kk * 4 + l4;
        af[m] = *(const bf16x8*)(&As[row * 64 + ((c ^ (row & 7)) * 8)]);
      }
#pragma unroll
      for (int n = 0; n < 4; ++n) {
        int row = wc * 64 + n * 16 + l15;
        int c = kk * 4 + l4;
        bfr[n] = *(const bf16x8*)(&Bs[row * 64 + ((c ^ (row & 7)) * 8)]);
      }
#pragma unroll
      for (int m = 0; m < 4; ++m)
#pragma unroll
        for (int n = 0; n < 4; ++n)
          acc[m][n] = __builtin_amdgcn_mfma_f32_16x16x32_bf16(af[m], bfr[n], acc[m][n], 0, 0, 0);
    }
  }
#pragma unroll
  for (int m = 0; m < 4; ++m)
#pragma unroll
    for (int n = 0; n < 4; ++n)
#pragma unroll
      for (int r = 0; r < 4; ++r) {
        long row = bm + wr * 64 + m * 16 + l4 * 4 + r;
        long col = bn + wc * 64 + n * 16 + l15;
        float v = acc[m][n][r];
        if constexpr (sizeof(OUT) == 2) C[row * ldc + col] = f2bf(v);
        else C[row * ldc + col] = v;
      }
}

// ---------------- RMSNorm, in-place, one block per row ----------------
template <int NCH>
__global__ __launch_bounds__(256) void rmsnorm_kernel(u16* __restrict__ buf,
                                                      const float* __restrict__ w, int stride) {
  const int tid = threadIdx.x;
  u16* p = buf + (size_t)blockIdx.x * stride;
  float x[NCH];
  float ss = 0.f;
#pragma unroll
  for (int i = 0; i < NCH; ++i) { x[i] = bf2f(p[tid + i * 256]); ss += x[i] * x[i]; }
#pragma unroll
  for (int off = 1; off < 64; off <<= 1) ss += __shfl_xor(ss, off);
  __shared__ float sred[4];
  if ((tid & 63) == 0) sred[tid >> 6] = ss;
  __syncthreads();
  float tot = sred[0] + sred[1] + sred[2] + sred[3];
  float rs = rsqrtf(tot / (float)(NCH * 256) + 1e-6f);
#pragma unroll
  for (int i = 0; i < NCH; ++i) p[tid + i * 256] = f2bf(x[i] * rs * w[tid + i * 256]);
}

// ---------------- RoPE on q_pe (in-place on q [4096][3072]) ----------------
__global__ __launch_bounds__(256) void rope_q_kernel(u16* __restrict__ q,
                                                     const float* __restrict__ cosb,
                                                     const float* __restrict__ sinb,
                                                     const float* __restrict__ gain) {
  int idx = blockIdx.x * 256 + threadIdx.x;  // B*S*H*32 = 2097152
  int i = idx & 31;
  int h = (idx >> 5) & 15;
  int srow = idx >> 9;             // 0..4095
  int s = srow & (S_LEN - 1);
  size_t base = (size_t)srow * 3072 + h * 192 + 128 + 2 * i;
  unsigned int* p = (unsigned int*)(q + base);
  unsigned int v = *p;
  float xe = bf2f((u16)(v & 0xffff)), xo = bf2f((u16)(v >> 16));
  float c = cosb[s * 32 + i], sn = sinb[s * 32 + i];
  float g = gain[h];
  float ye = (xe * c - xo * sn) * g, yo = (xe * sn + xo * c) * g;
  *p = (unsigned int)f2bf(ye) | ((unsigned int)f2bf(yo) << 16);
}

// ---------------- RoPE on k_pe (in-place on kv [4096][640], cols 512..576) ----------------
__global__ __launch_bounds__(256) void rope_k_kernel(u16* __restrict__ kv,
                                                     const float* __restrict__ cosb,
                                                     const float* __restrict__ sinb) {
  int idx = blockIdx.x * 256 + threadIdx.x;  // 4096*32 = 131072
  int i = idx & 31;
  int srow = idx >> 5;
  int s = srow & (S_LEN - 1);
  size_t base = (size_t)srow * 640 + 512 + 2 * i;
  unsigned int* p = (unsigned int*)(kv + base);
  unsigned int v = *p;
  float xe = bf2f((u16)(v & 0xffff)), xo = bf2f((u16)(v >> 16));
  float c = cosb[s * 32 + i], sn = sinb[s * 32 + i];
  *p = (unsigned int)f2bf(xe * c - xo * sn) | ((unsigned int)f2bf(xe * sn + xo * c) << 16);
}

// ---------------- assemble K [B*H][S][192] = [k_nope | k_pe] ----------------
__global__ __launch_bounds__(256) void k_assemble_kernel(const u16* __restrict__ kvb,
                                                         const u16* __restrict__ kv,
                                                         u16* __restrict__ Kb) {
  int idx = blockIdx.x * 256 + threadIdx.x;  // 65536*24
  int c = idx % 24;
  int rowid = idx / 24;            // (b*16+h)*2048 + s
  int bh = rowid >> 11, s = rowid & 2047;
  int b = bh >> 4, h = bh & 15;
  long srow = (long)b * S_LEN + s;
  u32x4 v;
  if (c < 16) v = *(const u32x4*)(kvb + srow * 4096 + h * 256 + c * 8);
  else        v = *(const u32x4*)(kv + srow * 640 + 512 + (c - 16) * 8);
  *(u32x4*)(Kb + (long)rowid * 192 + c * 8) = v;
}

// ---------------- V transpose: VT [B*H][128][S] ----------------
__global__ __launch_bounds__(256) void v_transpose_kernel(const u16* __restrict__ kvb,
                                                          u16* __restrict__ VT) {
  __shared__ u16 tile[32][33];
  int bh = blockIdx.z;
  int d0 = blockIdx.y * 32;
  int t0 = blockIdx.x * 32;
  int b = bh >> 4, h = bh & 15;
  int tx = threadIdx.x & 31, ty = threadIdx.x >> 5;
#pragma unroll
  for (int j = 0; j < 4; ++j) {
    int t = ty + j * 8;
    tile[t][tx] = kvb[((long)b * S_LEN + t0 + t) * 4096 + h * 256 + 128 + d0 + tx];
  }
  __syncthreads();
#pragma unroll
  for (int j = 0; j < 4; ++j) {
    int d = ty + j * 8;
    VT[((long)bh * 128 + d0 + d) * S_LEN + t0 + tx] = tile[tx][d];
  }
}

// ---------------- fused causal attention with softcap ----------------
// block: 256 thr / 4 waves, 64-query tile (16 rows per wave), 64-key tiles.
#define QT 64
#define KT 64
__global__ __launch_bounds__(256) void attn_kernel(const u16* __restrict__ Qg,
                                                   const u16* __restrict__ Kg,
                                                   const u16* __restrict__ VTg,
                                                   u16* __restrict__ Yg) {
  __shared__ u16 Ks[KT * 192];
  __shared__ u16 VTs[128 * KT];
  __shared__ u16 Ps[QT * KT];

  const int tid = threadIdx.x, lane = tid & 63, wid = tid >> 6;
  const int l15 = lane & 15, l4 = lane >> 4;

  int idx = blockIdx.x;
  int qt = 31 - (idx & 31);        // big tiles first (load balance)
  int bh = idx >> 5;
  int b = bh >> 4, h = bh & 15;
  int q0 = qt * QT;

  bf16x8 qf[6];
  {
    const u16* qbase = Qg + ((long)b * S_LEN + q0 + wid * 16 + l15) * 3072 + h * 192;
#pragma unroll
    for (int f = 0; f < 6; ++f) qf[f] = *(const bf16x8*)(qbase + f * 32 + 8 * l4);
  }

  f32x4 o[8] = {};
  float m[4], l[4];
#pragma unroll
  for (int r = 0; r < 4; ++r) { m[r] = -1e30f; l[r] = 0.f; }

  const u16* Kbh = Kg + (long)bh * S_LEN * 192;
  const u16* Vbh = VTg + (long)bh * 128 * S_LEN;

  const int ntiles = qt + 1;
  for (int it = 0; it < ntiles; ++it) {
    int k0 = it * KT;
    __syncthreads();
#pragma unroll
    for (int i = 0; i < 6; ++i) {        // K tile: 64 rows x 24 chunks
      int flat = i * 256 + tid;
      int row = flat / 24, c = flat % 24;
      *(u32x4*)(&Ks[row * 192 + ((c ^ (row & 7)) * 8)]) =
          *(const u32x4*)(Kbh + (long)(k0 + row) * 192 + c * 8);
    }
#pragma unroll
    for (int i = 0; i < 4; ++i) {        // VT tile: 128 rows x 8 chunks
      int flat = i * 256 + tid;
      int row = flat >> 3, c = flat & 7;
      *(u32x4*)(&VTs[row * KT + ((c ^ (row & 7)) * 8)]) =
          *(const u32x4*)(Vbh + (long)row * S_LEN + k0 + c * 8);
    }
    __syncthreads();

    f32x4 sacc[4] = {};
#pragma unroll
    for (int f = 0; f < 6; ++f)
#pragma unroll
      for (int tf = 0; tf < 4; ++tf) {
        int row = tf * 16 + l15;
        int c = f * 4 + l4;
        bf16x8 kf = *(const bf16x8*)(&Ks[row * 192 + ((c ^ (row & 7)) * 8)]);
        sacc[tf] = __builtin_amdgcn_mfma_f32_16x16x32_bf16(qf[f], kf, sacc[tf], 0, 0, 0);
      }

    const bool diag = (k0 == q0);
    float sv[4][4];
    float rowmax[4] = {-1e30f, -1e30f, -1e30f, -1e30f};
#pragma unroll
    for (int tf = 0; tf < 4; ++tf)
#pragma unroll
      for (int r = 0; r < 4; ++r) {
        float x = sacc[tf][r] * 0.07216878364870323f;  // 192^-0.5
        float e = __expf(x * (1.0f / 15.0f));          // 30*tanh(x/30)
        x = 30.f - 60.f / (e + 1.f);
        if (diag) {
          int t = k0 + tf * 16 + l15;
          int srow = q0 + wid * 16 + l4 * 4 + r;
          if (t > srow) x = -1e30f;
        }
        sv[tf][r] = x;
        rowmax[r] = fmaxf(rowmax[r], x);
      }
#pragma unroll
    for (int r = 0; r < 4; ++r) {
      rowmax[r] = fmaxf(rowmax[r], __shfl_xor(rowmax[r], 1));
      rowmax[r] = fmaxf(rowmax[r], __shfl_xor(rowmax[r], 2));
      rowmax[r] = fmaxf(rowmax[r], __shfl_xor(rowmax[r], 4));
      rowmax[r] = fmaxf(rowmax[r], __shfl_xor(rowmax[r], 8));
    }
    float alpha[4], rowsum[4];
#pragma unroll
    for (int r = 0; r < 4; ++r) {
      float mn = fmaxf(m[r], rowmax[r]);
      alpha[r] = __expf(m[r] - mn);
      m[r] = mn;
      rowsum[r] = 0.f;
    }
#pragma unroll
    for (int tf = 0; tf < 4; ++tf)
#pragma unroll
      for (int r = 0; r < 4; ++r) {
        float p = __expf(sv[tf][r] - m[r]);
        rowsum[r] += p;
        int prow = wid * 16 + l4 * 4 + r;
        int col = tf * 16 + l15;
        int pc = col >> 3, pe = col & 7;
        Ps[prow * KT + ((pc ^ (prow & 7)) * 8) + pe] = f2bf(p);
      }
#pragma unroll
    for (int r = 0; r < 4; ++r) {
      rowsum[r] += __shfl_xor(rowsum[r], 1);
      rowsum[r] += __shfl_xor(rowsum[r], 2);
      rowsum[r] += __shfl_xor(rowsum[r], 4);
      rowsum[r] += __shfl_xor(rowsum[r], 8);
      l[r] = l[r] * alpha[r] + rowsum[r];
    }
#pragma unroll
    for (int nf = 0; nf < 8; ++nf)
#pragma unroll
      for (int r = 0; r < 4; ++r) o[nf][r] *= alpha[r];

#pragma unroll
    for (int kk = 0; kk < 2; ++kk) {
      int prow = wid * 16 + l15;
      int c = kk * 4 + l4;
      bf16x8 pf = *(const bf16x8*)(&Ps[prow * KT + ((c ^ (prow & 7)) * 8)]);
#pragma unroll
      for (int nf = 0; nf < 8; ++nf) {
        int vrow = nf * 16 + l15;
        bf16x8 vf = *(const bf16x8*)(&VTs[vrow * KT + ((c ^ (vrow & 7)) * 8)]);
        o[nf] = __builtin_amdgcn_mfma_f32_16x16x32_bf16(pf, vf, o[nf], 0, 0, 0);
      }
    }
  }

#pragma unroll
  for (int nf = 0; nf < 8; ++nf)
#pragma unroll
    for (int r = 0; r < 4; ++r) {
      long row = (long)b * S_LEN + q0 + wid * 16 + l4 * 4 + r;
      int col = h * 128 + nf * 16 + l15;
      Yg[row * 2048 + col] = f2bf(o[nf][r] / l[r]);
    }
}

// ---------------- v-projection removal: y -= (y.vn)vn, vn = v/|v| ----------------
__global__ __launch_bounds__(256) void vproj_kernel(u16* __restrict__ Y,
                                                    const u16* __restrict__ kvb) {
  int wid = threadIdx.x >> 6, lane = threadIdx.x & 63;
  long rowh = (long)blockIdx.x * 4 + wid;  // (b*S+s)*16 + h
  long srow = rowh >> 4;
  int h = rowh & 15;
  const u16* vptr = kvb + srow * 4096 + h * 256 + 128;
  u16* yptr = Y + srow * 2048 + h * 128;
  unsigned int vv = *(const unsigned int*)(vptr + lane * 2);
  unsigned int yy = *(const unsigned int*)(yptr + lane * 2);
  float v0 = bf2f((u16)(vv & 0xffff)), v1 = bf2f((u16)(vv >> 16));
  float y0 = bf2f((u16)(yy & 0xffff)), y1 = bf2f((u16)(yy >> 16));
  float ss = v0 * v0 + v1 * v1;
#pragma unroll
  for (int off = 1; off < 64; off <<= 1) ss += __shfl_xor(ss, off);
  float inv = rsqrtf(fmaxf(ss, 1e-12f));
  float vn0 = v0 * inv, vn1 = v1 * inv;
  float dot = y0 * vn0 + y1 * vn1;
#pragma unroll
  for (int off = 1; off < 64; off <<= 1) dot += __shfl_xor(dot, off);
  y0 -= dot * vn0;
  y1 -= dot * vn1;
  *(unsigned int*)(yptr + lane * 2) = (unsigned int)f2bf(y0) | ((unsigned int)f2bf(y1) << 16);
}

extern "C" void kernel_launch(void* const* d_in, const int* in_sizes, int n_in,
                              void* d_out, int out_size, void* d_ws, size_t ws_size,
                              hipStream_t stream) {
  const float* x       = (const float*)d_in[0];
  const float* wq_a    = (const float*)d_in[1];
  const float* q_norm  = (const float*)d_in[2];
  const float* wq_b    = (const float*)d_in[3];
  const float* q_gain  = (const float*)d_in[4];
  const float* wkv_a   = (const float*)d_in[5];
  const float* kv_norm = (const float*)d_in[6];
  const float* wkv_b   = (const float*)d_in[7];
  const float* wo      = (const float*)d_in[8];
  const float* fcos    = (const float*)d_in[9];
  const float* fsin    = (const float*)d_in[10];
  float* out = (float*)d_out;

  char* ws = (char*)d_ws;
  size_t off = 0;
  auto alloc = [&](size_t bytes) {
    char* p = ws + off;
    off += (bytes + 255) & ~(size_t)255;
    return p;
  };
  const long M = 4096;  // B*S
  u16* xb    = (u16*)alloc(M * 2048 * 2);
  u16* wqab  = (u16*)alloc(768L * 2048 * 2);
  u16* wqbb  = (u16*)alloc(3072L * 768 * 2);
  u16* wkvab = (u16*)alloc(640L * 2048 * 2);
  u16* wkvbb = (u16*)alloc(4096L * 512 * 2);
  u16* wob   = (u16*)alloc(2048L * 2048 * 2);
  u16* qa    = (u16*)alloc(M * 768 * 2);
  u16* qb    = (u16*)alloc(M * 3072 * 2);
  u16* kv    = (u16*)alloc(M * 640 * 2);
  u16* kvbb  = (u16*)alloc(M * 4096 * 2);
  u16* Kb    = (u16*)alloc(32L * 2048 * 192 * 2);
  u16* VTb   = (u16*)alloc(32L * 128 * 2048 * 2);
  u16* Yb    = (u16*)alloc(M * 2048 * 2);

  auto cast = [&](const float* s, u16* d, long n) {
    long n4 = n / 4;
    cast_f32_bf16<<<(n4 + 255) / 256, 256, 0, stream>>>(s, d, n4);
  };
  cast(x, xb, M * 2048);
  cast(wq_a, wqab, 768L * 2048);
  cast(wq_b, wqbb, 3072L * 768);
  cast(wkv_b, wkvbb, 4096L * 512);
  cast(wo, wob, 2048L * 2048);
  {
    long n4 = 640L * 2048 / 4;
    cast_pad<<<(n4 + 255) / 256, 256, 0, stream>>>(wkv_a, wkvab, 576, n4, 2048);
  }

  // q_a = rms_norm(x @ wq_a^T)
  gemm_nt<u16><<<dim3(6, 32), 256, 0, stream>>>(xb, 2048, wqab, 2048, qa, 768, 2048);
  rmsnorm_kernel<3><<<4096, 256, 0, stream>>>(qa, q_norm, 768);
  // q = q_a @ wq_b^T
  gemm_nt<u16><<<dim3(24, 32), 256, 0, stream>>>(qa, 768, wqbb, 768, qb, 3072, 768);
  // kv_full = x @ wkv_a^T (N padded to 640)
  gemm_nt<u16><<<dim3(5, 32), 256, 0, stream>>>(xb, 2048, wkvab, 2048, kv, 640, 2048);
  rmsnorm_kernel<2><<<4096, 256, 0, stream>>>(kv, kv_norm, 640);
  rope_q_kernel<<<2097152 / 256, 256, 0, stream>>>(qb, fcos, fsin, q_gain);
  rope_k_kernel<<<131072 / 256, 256, 0, stream>>>(kv, fcos, fsin);
  // kvb = kv_norm @ wkv_b^T
  gemm_nt<u16><<<dim3(32, 32), 256, 0, stream>>>(kv, 640, wkvbb, 512, kvbb, 4096, 512);
  k_assemble_kernel<<<1572864 / 256, 256, 0, stream>>>(kvbb, kv, Kb);
  v_transpose_kernel<<<dim3(64, 4, 32), 256, 0, stream>>>(kvbb, VTb);
  attn_kernel<<<1024, 256, 0, stream>>>(qb, Kb, VTb, Yb);
  vproj_kernel<<<16384, 256, 0, stream>>>(Yb, kvbb);
  // out = y @ wo^T (f32 out)
  gemm_nt<float><<<dim3(16, 32), 256, 0, stream>>>(Yb, 2048, wob, 2048, out, 2048, 2048);
}

// Round 2
// 380.302 us; speedup vs baseline: 1.3334x; 1.3334x over previous
//
#include <hip/hip_runtime.h>
#include <stdint.h>

typedef unsigned short u16;
typedef __bf16 bf16x8 __attribute__((ext_vector_type(8)));
typedef float f32x4 __attribute__((ext_vector_type(4)));
typedef unsigned int u32x4 __attribute__((ext_vector_type(4)));

typedef __attribute__((address_space(3))) void LDSV;
typedef __attribute__((address_space(1))) void GLV;

#define S_LEN 2048
#define NHEAD 16

__device__ __forceinline__ float bf2f(u16 u) {
  union { unsigned int i; float f; } v; v.i = ((unsigned int)u) << 16; return v.f;
}
__device__ __forceinline__ u16 f2bf(float f) {
  union { float f; unsigned int i; } v; v.f = f;
  unsigned int x = v.i;
  return (u16)((x + 0x7fffu + ((x >> 16) & 1u)) >> 16);
}

// ---------------- cast kernels ----------------
__global__ __launch_bounds__(256) void cast_f32_bf16(const float* __restrict__ src,
                                                     u16* __restrict__ dst, long n4) {
  long i = (long)blockIdx.x * 256 + threadIdx.x;
  if (i >= n4) return;
  float4 v = ((const float4*)src)[i];
  unsigned long long r = (unsigned long long)f2bf(v.x)
                       | ((unsigned long long)f2bf(v.y) << 16)
                       | ((unsigned long long)f2bf(v.z) << 32)
                       | ((unsigned long long)f2bf(v.w) << 48);
  ((unsigned long long*)dst)[i] = r;
}

// pad rows >= src_rows with zeros (wkv_a: 576 -> 640 rows)
__global__ __launch_bounds__(256) void cast_pad(const float* __restrict__ src,
                                                u16* __restrict__ dst, int src_rows,
                                                long n4, int cols) {
  long i = (long)blockIdx.x * 256 + threadIdx.x;
  if (i >= n4) return;
  long e0 = i * 4;
  int row = (int)(e0 / cols);
  unsigned long long r = 0;
  if (row < src_rows) {
    float4 v = *(const float4*)(src + e0);
    r = (unsigned long long)f2bf(v.x)
      | ((unsigned long long)f2bf(v.y) << 16)
      | ((unsigned long long)f2bf(v.z) << 32)
      | ((unsigned long long)f2bf(v.w) << 48);
  }
  ((unsigned long long*)dst)[i] = r;
}

// ---------------- NT GEMM: C[M][N] = A[M][K] * B[N][K]^T ----------------
// m97 structure: 128x128 tile, BK=64, 4 waves, global_load_lds w16, linear LDS.
template <typename OUT>
__global__ __launch_bounds__(256) void gemm_nt(const u16* __restrict__ A, int lda,
                                               const u16* __restrict__ B, int ldb,
                                               OUT* __restrict__ C, int ldc, int K) {
  __shared__ u16 As[128 * 64];
  __shared__ u16 Bs[128 * 64];
  const int tid = threadIdx.x;
  const int lane = tid & 63, wid = tid >> 6;
  const int l15 = lane & 15, l4 = lane >> 4;
  const int wr = wid >> 1, wc = wid & 1;
  const long bm = (long)blockIdx.y * 128;
  const long bn = (long)blockIdx.x * 128;

  // staging: wave w covers rows [w*32, w*32+32); per instr: 8 rows x 64 cols = 1KB
  const int srow = wid * 32 + (lane >> 3);
  const int scol = (lane & 7) * 8;
  const u16* Ag = A + (bm + srow) * (long)lda + scol;
  const u16* Bg = B + (bn + srow) * (long)ldb + scol;
  u16* AsW = &As[wid * 32 * 64];
  u16* BsW = &Bs[wid * 32 * 64];

  f32x4 acc[4][4] = {};

  for (int k0 = 0; k0 < K; k0 += 64) {
    __syncthreads();  // previous tile fully consumed
#pragma unroll
    for (int ch = 0; ch < 4; ++ch) {
      __builtin_amdgcn_global_load_lds((const GLV*)(Ag + (long)ch * 8 * lda + k0),
                                       (LDSV*)(AsW + ch * 512), 16, 0, 0);
      __builtin_amdgcn_global_load_lds((const GLV*)(Bg + (long)ch * 8 * ldb + k0),
                                       (LDSV*)(BsW + ch * 512), 16, 0, 0);
    }
    __syncthreads();  // compiler drains vmcnt(0) before barrier -> tile ready
#pragma unroll
    for (int kk = 0; kk < 2; ++kk) {
      bf16x8 af[4], bfr[4];
#pragma unroll
      for (int m = 0; m < 4; ++m)
        af[m] = *(const bf16x8*)(&As[(wr * 64 + m * 16 + l15) * 64 + (kk * 4 + l4) * 8]);
#pragma unroll
      for (int n = 0; n < 4; ++n)
        bfr[n] = *(const bf16x8*)(&Bs[(wc * 64 + n * 16 + l15) * 64 + (kk * 4 + l4) * 8]);
#pragma unroll
      for (int m = 0; m < 4; ++m)
#pragma unroll
        for (int n = 0; n < 4; ++n)
          acc[m][n] = __builtin_amdgcn_mfma_f32_16x16x32_bf16(af[m], bfr[n], acc[m][n], 0, 0, 0);
    }
  }
#pragma unroll
  for (int m = 0; m < 4; ++m)
#pragma unroll
    for (int n = 0; n < 4; ++n)
#pragma unroll
      for (int r = 0; r < 4; ++r) {
        long row = bm + wr * 64 + m * 16 + l4 * 4 + r;
        long col = bn + wc * 64 + n * 16 + l15;
        float v = acc[m][n][r];
        if constexpr (sizeof(OUT) == 2) C[row * ldc + col] = f2bf(v);
        else C[row * ldc + col] = v;
      }
}

// ---------------- RMSNorm, in-place, one block per row ----------------
template <int NCH>
__global__ __launch_bounds__(256) void rmsnorm_kernel(u16* __restrict__ buf,
                                                      const float* __restrict__ w, int stride) {
  const int tid = threadIdx.x;
  u16* p = buf + (size_t)blockIdx.x * stride;
  float x[NCH];
  float ss = 0.f;
#pragma unroll
  for (int i = 0; i < NCH; ++i) { x[i] = bf2f(p[tid + i * 256]); ss += x[i] * x[i]; }
#pragma unroll
  for (int off = 1; off < 64; off <<= 1) ss += __shfl_xor(ss, off);
  __shared__ float sred[4];
  if ((tid & 63) == 0) sred[tid >> 6] = ss;
  __syncthreads();
  float tot = sred[0] + sred[1] + sred[2] + sred[3];
  float rs = rsqrtf(tot / (float)(NCH * 256) + 1e-6f);
#pragma unroll
  for (int i = 0; i < NCH; ++i) p[tid + i * 256] = f2bf(x[i] * rs * w[tid + i * 256]);
}

// ---------------- RoPE on q_pe (in-place on q [4096][3072]) ----------------
__global__ __launch_bounds__(256) void rope_q_kernel(u16* __restrict__ q,
                                                     const float* __restrict__ cosb,
                                                     const float* __restrict__ sinb,
                                                     const float* __restrict__ gain) {
  int idx = blockIdx.x * 256 + threadIdx.x;  // B*S*H*32 = 2097152
  int i = idx & 31;
  int h = (idx >> 5) & 15;
  int srow = idx >> 9;             // 0..4095
  int s = srow & (S_LEN - 1);
  size_t base = (size_t)srow * 3072 + h * 192 + 128 + 2 * i;
  unsigned int* p = (unsigned int*)(q + base);
  unsigned int v = *p;
  float xe = bf2f((u16)(v & 0xffff)), xo = bf2f((u16)(v >> 16));
  float c = cosb[s * 32 + i], sn = sinb[s * 32 + i];
  float g = gain[h];
  float ye = (xe * c - xo * sn) * g, yo = (xe * sn + xo * c) * g;
  *p = (unsigned int)f2bf(ye) | ((unsigned int)f2bf(yo) << 16);
}

// ---------------- RoPE on k_pe (in-place on kv [4096][640], cols 512..576) ----------------
__global__ __launch_bounds__(256) void rope_k_kernel(u16* __restrict__ kv,
                                                     const float* __restrict__ cosb,
                                                     const float* __restrict__ sinb) {
  int idx = blockIdx.x * 256 + threadIdx.x;  // 4096*32 = 131072
  int i = idx & 31;
  int srow = idx >> 5;
  int s = srow & (S_LEN - 1);
  size_t base = (size_t)srow * 640 + 512 + 2 * i;
  unsigned int* p = (unsigned int*)(kv + base);
  unsigned int v = *p;
  float xe = bf2f((u16)(v & 0xffff)), xo = bf2f((u16)(v >> 16));
  float c = cosb[s * 32 + i], sn = sinb[s * 32 + i];
  *p = (unsigned int)f2bf(xe * c - xo * sn) | ((unsigned int)f2bf(xe * sn + xo * c) << 16);
}

// ---------------- assemble K [B*H][S][192] = [k_nope | k_pe] ----------------
__global__ __launch_bounds__(256) void k_assemble_kernel(const u16* __restrict__ kvb,
                                                         const u16* __restrict__ kv,
                                                         u16* __restrict__ Kb) {
  int idx = blockIdx.x * 256 + threadIdx.x;  // 65536*24
  int c = idx % 24;
  int rowid = idx / 24;            // (b*16+h)*2048 + s
  int bh = rowid >> 11, s = rowid & 2047;
  int b = bh >> 4, h = bh & 15;
  long srow = (long)b * S_LEN + s;
  u32x4 v;
  if (c < 16) v = *(const u32x4*)(kvb + srow * 4096 + h * 256 + c * 8);
  else        v = *(const u32x4*)(kv + srow * 640 + 512 + (c - 16) * 8);
  *(u32x4*)(Kb + (long)rowid * 192 + c * 8) = v;
}

// ---------------- V transpose: VT [B*H][128][S] ----------------
__global__ __launch_bounds__(256) void v_transpose_kernel(const u16* __restrict__ kvb,
                                                          u16* __restrict__ VT) {
  __shared__ u16 tile[32][33];
  int bh = blockIdx.z;
  int d0 = blockIdx.y * 32;
  int t0 = blockIdx.x * 32;
  int b = bh >> 4, h = bh & 15;
  int tx = threadIdx.x & 31, ty = threadIdx.x >> 5;
#pragma unroll
  for (int j = 0; j < 4; ++j) {
    int t = ty + j * 8;
    tile[t][tx] = kvb[((long)b * S_LEN + t0 + t) * 4096 + h * 256 + 128 + d0 + tx];
  }
  __syncthreads();
#pragma unroll
  for (int j = 0; j < 4; ++j) {
    int d = ty + j * 8;
    VT[((long)bh * 128 + d0 + d) * S_LEN + t0 + tx] = tile[tx][d];
  }
}

// ---------------- fused causal attention with softcap ----------------
// Fixed softmax reference m=30 (softcap bounds scores to [-30,30]) -> no online
// max, no rescale. Paired q-tiles (qt, 31-qt): every block = exactly 33 k-tiles.
// grid = 512 = 2 blocks/CU, all co-resident. Reg-prefetch of next K/V tile (T14).
#define QT 64
#define KT 64
__global__ __launch_bounds__(256, 2) void attn_kernel(const u16* __restrict__ Qg,
                                                      const u16* __restrict__ Kg,
                                                      const u16* __restrict__ VTg,
                                                      u16* __restrict__ Yg) {
  __shared__ u16 Ks[KT * 192];
  __shared__ u16 VTs[128 * KT];
  __shared__ u16 Ps[QT * KT];

  const int tid = threadIdx.x, lane = tid & 63, wid = tid >> 6;
  const int l15 = lane & 15, l4 = lane >> 4;

  const int idx = blockIdx.x;      // 512 blocks = 32 bh x 16 pairs
  const int pr = idx & 15;
  const int bh = idx >> 4;
  const int b = bh >> 4, h = bh & 15;

  const u16* Kbh = Kg + (long)bh * S_LEN * 192;
  const u16* Vbh = VTg + (long)bh * 128 * S_LEN;

  int krow[6], kc[6];
#pragma unroll
  for (int i = 0; i < 6; ++i) { int flat = i * 256 + tid; krow[i] = flat / 24; kc[i] = flat % 24; }

  // p = exp(t-30), t = 30*tanh(s*SCALE/30) => p = exp2(c2 * rcp(exp2(s*c1)+1))
  const float c1 = 0.07216878364870323f * 0.09617966939259756f;  // SCALE*log2(e)/15
  const float c2 = -86.56170245333781f;                          // -60*log2(e)

  for (int seg = 0; seg < 2; ++seg) {
    const int qt = (seg == 0) ? 31 - pr : pr;
    const int q0 = qt * QT;

    bf16x8 qf[6];
    {
      const u16* qbase = Qg + ((long)b * S_LEN + q0 + wid * 16 + l15) * 3072 + h * 192;
#pragma unroll
      for (int f = 0; f < 6; ++f) qf[f] = *(const bf16x8*)(qbase + f * 32 + 8 * l4);
    }

    f32x4 o[8] = {};
    float lsum[4] = {0.f, 0.f, 0.f, 0.f};

    u32x4 ka[6], va[4];
#pragma unroll
    for (int i = 0; i < 6; ++i)
      ka[i] = *(const u32x4*)(Kbh + (long)krow[i] * 192 + kc[i] * 8);
#pragma unroll
    for (int i = 0; i < 4; ++i) {
      int flat = i * 256 + tid;
      va[i] = *(const u32x4*)(Vbh + (long)(flat >> 3) * S_LEN + (flat & 7) * 8);
    }

    for (int it = 0; it <= qt; ++it) {
      __syncthreads();
#pragma unroll
      for (int i = 0; i < 6; ++i)
        *(u32x4*)(&Ks[krow[i] * 192 + ((kc[i] ^ (krow[i] & 7)) * 8)]) = ka[i];
#pragma unroll
      for (int i = 0; i < 4; ++i) {
        int flat = i * 256 + tid; int row = flat >> 3, c = flat & 7;
        *(u32x4*)(&VTs[row * KT + ((c ^ (row & 7)) * 8)]) = va[i];
      }
      __syncthreads();
      if (it < qt) {  // prefetch next tile; latency hides under compute
        int k0n = (it + 1) * KT;
#pragma unroll
        for (int i = 0; i < 6; ++i)
          ka[i] = *(const u32x4*)(Kbh + (long)(k0n + krow[i]) * 192 + kc[i] * 8);
#pragma unroll
        for (int i = 0; i < 4; ++i) {
          int flat = i * 256 + tid;
          va[i] = *(const u32x4*)(Vbh + (long)(flat >> 3) * S_LEN + k0n + (flat & 7) * 8);
        }
      }

      f32x4 sacc[4] = {};
#pragma unroll
      for (int f = 0; f < 6; ++f)
#pragma unroll
        for (int tf = 0; tf < 4; ++tf) {
          int row = tf * 16 + l15;
          int c = f * 4 + l4;
          bf16x8 kf = *(const bf16x8*)(&Ks[row * 192 + ((c ^ (row & 7)) * 8)]);
          sacc[tf] = __builtin_amdgcn_mfma_f32_16x16x32_bf16(qf[f], kf, sacc[tf], 0, 0, 0);
        }

      const bool diag = (it == qt);
#pragma unroll
      for (int tf = 0; tf < 4; ++tf)
#pragma unroll
        for (int r = 0; r < 4; ++r) {
          float u = __builtin_amdgcn_exp2f(sacc[tf][r] * c1);
          float p = __builtin_amdgcn_exp2f(c2 * __builtin_amdgcn_rcpf(u + 1.0f));
          if (diag && (tf * 16 + l15 > wid * 16 + l4 * 4 + r)) p = 0.f;
          lsum[r] += p;
          int prow = wid * 16 + l4 * 4 + r;
          int col = tf * 16 + l15;
          int pc = col >> 3, pe = col & 7;
          Ps[prow * KT + ((pc ^ (prow & 7)) * 8) + pe] = f2bf(p);
        }

#pragma unroll
      for (int kk = 0; kk < 2; ++kk) {
        int prow = wid * 16 + l15;
        int c = kk * 4 + l4;
        bf16x8 pf = *(const bf16x8*)(&Ps[prow * KT + ((c ^ (prow & 7)) * 8)]);
#pragma unroll
        for (int nf = 0; nf < 8; ++nf) {
          int vrow = nf * 16 + l15;
          bf16x8 vf = *(const bf16x8*)(&VTs[vrow * KT + ((c ^ (vrow & 7)) * 8)]);
          o[nf] = __builtin_amdgcn_mfma_f32_16x16x32_bf16(pf, vf, o[nf], 0, 0, 0);
        }
      }
    }

#pragma unroll
    for (int r = 0; r < 4; ++r) {
      lsum[r] += __shfl_xor(lsum[r], 1);
      lsum[r] += __shfl_xor(lsum[r], 2);
      lsum[r] += __shfl_xor(lsum[r], 4);
      lsum[r] += __shfl_xor(lsum[r], 8);
      lsum[r] = __builtin_amdgcn_rcpf(lsum[r]);
    }
#pragma unroll
    for (int nf = 0; nf < 8; ++nf)
#pragma unroll
      for (int r = 0; r < 4; ++r) {
        long row = (long)b * S_LEN + q0 + wid * 16 + l4 * 4 + r;
        int col = h * 128 + nf * 16 + l15;
        Yg[row * 2048 + col] = f2bf(o[nf][r] * lsum[r]);
      }
  }
}

// ---------------- v-projection removal: y -= (y.vn)vn, vn = v/|v| ----------------
__global__ __launch_bounds__(256) void vproj_kernel(u16* __restrict__ Y,
                                                    const u16* __restrict__ kvb) {
  int wid = threadIdx.x >> 6, lane = threadIdx.x & 63;
  long rowh = (long)blockIdx.x * 4 + wid;  // (b*S+s)*16 + h
  long srow = rowh >> 4;
  int h = rowh & 15;
  const u16* vptr = kvb + srow * 4096 + h * 256 + 128;
  u16* yptr = Y + srow * 2048 + h * 128;
  unsigned int vv = *(const unsigned int*)(vptr + lane * 2);
  unsigned int yy = *(const unsigned int*)(yptr + lane * 2);
  float v0 = bf2f((u16)(vv & 0xffff)), v1 = bf2f((u16)(vv >> 16));
  float y0 = bf2f((u16)(yy & 0xffff)), y1 = bf2f((u16)(yy >> 16));
  float ss = v0 * v0 + v1 * v1;
#pragma unroll
  for (int off = 1; off < 64; off <<= 1) ss += __shfl_xor(ss, off);
  float inv = rsqrtf(fmaxf(ss, 1e-12f));
  float vn0 = v0 * inv, vn1 = v1 * inv;
  float dot = y0 * vn0 + y1 * vn1;
#pragma unroll
  for (int off = 1; off < 64; off <<= 1) dot += __shfl_xor(dot, off);
  y0 -= dot * vn0;
  y1 -= dot * vn1;
  *(unsigned int*)(yptr + lane * 2) = (unsigned int)f2bf(y0) | ((unsigned int)f2bf(y1) << 16);
}

extern "C" void kernel_launch(void* const* d_in, const int* in_sizes, int n_in,
                              void* d_out, int out_size, void* d_ws, size_t ws_size,
                              hipStream_t stream) {
  const float* x       = (const float*)d_in[0];
  const float* wq_a    = (const float*)d_in[1];
  const float* q_norm  = (const float*)d_in[2];
  const float* wq_b    = (const float*)d_in[3];
  const float* q_gain  = (const float*)d_in[4];
  const float* wkv_a   = (const float*)d_in[5];
  const float* kv_norm = (const float*)d_in[6];
  const float* wkv_b   = (const float*)d_in[7];
  const float* wo      = (const float*)d_in[8];
  const float* fcos    = (const float*)d_in[9];
  const float* fsin    = (const float*)d_in[10];
  float* out = (float*)d_out;

  char* ws = (char*)d_ws;
  size_t off = 0;
  auto alloc = [&](size_t bytes) {
    char* p = ws + off;
    off += (bytes + 255) & ~(size_t)255;
    return p;
  };
  const long M = 4096;  // B*S
  u16* xb    = (u16*)alloc(M * 2048 * 2);
  u16* wqab  = (u16*)alloc(768L * 2048 * 2);
  u16* wqbb  = (u16*)alloc(3072L * 768 * 2);
  u16* wkvab = (u16*)alloc(640L * 2048 * 2);
  u16* wkvbb = (u16*)alloc(4096L * 512 * 2);
  u16* wob   = (u16*)alloc(2048L * 2048 * 2);
  u16* qa    = (u16*)alloc(M * 768 * 2);
  u16* qb    = (u16*)alloc(M * 3072 * 2);
  u16* kv    = (u16*)alloc(M * 640 * 2);
  u16* kvbb  = (u16*)alloc(M * 4096 * 2);
  u16* Kb    = (u16*)alloc(32L * 2048 * 192 * 2);
  u16* VTb   = (u16*)alloc(32L * 128 * 2048 * 2);
  u16* Yb    = (u16*)alloc(M * 2048 * 2);

  auto cast = [&](const float* s, u16* d, long n) {
    long n4 = n / 4;
    cast_f32_bf16<<<(n4 + 255) / 256, 256, 0, stream>>>(s, d, n4);
  };
  cast(x, xb, M * 2048);
  cast(wq_a, wqab, 768L * 2048);
  cast(wq_b, wqbb, 3072L * 768);
  cast(wkv_b, wkvbb, 4096L * 512);
  cast(wo, wob, 2048L * 2048);
  {
    long n4 = 640L * 2048 / 4;
    cast_pad<<<(n4 + 255) / 256, 256, 0, stream>>>(wkv_a, wkvab, 576, n4, 2048);
  }

  // q_a = rms_norm(x @ wq_a^T)
  gemm_nt<u16><<<dim3(6, 32), 256, 0, stream>>>(xb, 2048, wqab, 2048, qa, 768, 2048);
  rmsnorm_kernel<3><<<4096, 256, 0, stream>>>(qa, q_norm, 768);
  // q = q_a @ wq_b^T
  gemm_nt<u16><<<dim3(24, 32), 256, 0, stream>>>(qa, 768, wqbb, 768, qb, 3072, 768);
  // kv_full = x @ wkv_a^T (N padded to 640)
  gemm_nt<u16><<<dim3(5, 32), 256, 0, stream>>>(xb, 2048, wkvab, 2048, kv, 640, 2048);
  rmsnorm_kernel<2><<<4096, 256, 0, stream>>>(kv, kv_norm, 640);
  rope_q_kernel<<<2097152 / 256, 256, 0, stream>>>(qb, fcos, fsin, q_gain);
  rope_k_kernel<<<131072 / 256, 256, 0, stream>>>(kv, fcos, fsin);
  // kvb = kv_norm @ wkv_b^T
  gemm_nt<u16><<<dim3(32, 32), 256, 0, stream>>>(kv, 640, wkvbb, 512, kvbb, 4096, 512);
  k_assemble_kernel<<<1572864 / 256, 256, 0, stream>>>(kvbb, kv, Kb);
  v_transpose_kernel<<<dim3(64, 4, 32), 256, 0, stream>>>(kvbb, VTb);
  attn_kernel<<<512, 256, 0, stream>>>(qb, Kb, VTb, Yb);
  vproj_kernel<<<16384, 256, 0, stream>>>(Yb, kvbb);
  // out = y @ wo^T (f32 out)
  gemm_nt<float><<<dim3(16, 32), 256, 0, stream>>>(Yb, 2048, wob, 2048, out, 2048, 2048);
}

// Round 3
// 315.170 us; speedup vs baseline: 1.6090x; 1.2067x over previous
//
#include <hip/hip_runtime.h>
#include <stdint.h>

typedef unsigned short u16;
typedef __bf16 bf16x8 __attribute__((ext_vector_type(8)));
typedef float f32x4 __attribute__((ext_vector_type(4)));
typedef unsigned int u32x4 __attribute__((ext_vector_type(4)));

typedef __attribute__((address_space(3))) void LDSV;
typedef __attribute__((address_space(1))) void GLV;

#define S_LEN 2048

__device__ __forceinline__ float bf2f(u16 u) {
  union { unsigned int i; float f; } v; v.i = ((unsigned int)u) << 16; return v.f;
}
__device__ __forceinline__ u16 f2bf(float f) {
  union { float f; unsigned int i; } v; v.f = f;
  unsigned int x = v.i;
  return (u16)((x + 0x7fffu + ((x >> 16) & 1u)) >> 16);
}

// ---------------- cast kernels ----------------
__global__ __launch_bounds__(256) void cast_f32_bf16(const float* __restrict__ src,
                                                     u16* __restrict__ dst, long n4) {
  long i = (long)blockIdx.x * 256 + threadIdx.x;
  if (i >= n4) return;
  float4 v = ((const float4*)src)[i];
  unsigned long long r = (unsigned long long)f2bf(v.x)
                       | ((unsigned long long)f2bf(v.y) << 16)
                       | ((unsigned long long)f2bf(v.z) << 32)
                       | ((unsigned long long)f2bf(v.w) << 48);
  ((unsigned long long*)dst)[i] = r;
}

__global__ __launch_bounds__(256) void cast_pad(const float* __restrict__ src,
                                                u16* __restrict__ dst, int src_rows,
                                                long n4, int cols) {
  long i = (long)blockIdx.x * 256 + threadIdx.x;
  if (i >= n4) return;
  long e0 = i * 4;
  int row = (int)(e0 / cols);
  unsigned long long r = 0;
  if (row < src_rows) {
    float4 v = *(const float4*)(src + e0);
    r = (unsigned long long)f2bf(v.x)
      | ((unsigned long long)f2bf(v.y) << 16)
      | ((unsigned long long)f2bf(v.z) << 32)
      | ((unsigned long long)f2bf(v.w) << 48);
  }
  ((unsigned long long*)dst)[i] = r;
}

// ---------------- NT GEMM: C[M][N] = A[M][K] * B[N][K]^T ----------------
// m97 structure: 128x128 tile, BK=64, 4 waves, global_load_lds w16, linear LDS.
// MODE 0: bf16 C[ldc];  MODE 1: f32 C[ldc];  MODE 2: split K-nope/V epilogue.
template <int MODE>
__global__ __launch_bounds__(256) void gemm_nt(const u16* __restrict__ A, int lda,
                                               const u16* __restrict__ B, int ldb,
                                               void* __restrict__ Cv, int ldc,
                                               u16* __restrict__ Vc, int K) {
  __shared__ u16 As[128 * 64];
  __shared__ u16 Bs[128 * 64];
  const int tid = threadIdx.x;
  const int lane = tid & 63, wid = tid >> 6;
  const int l15 = lane & 15, l4 = lane >> 4;
  const int wr = wid >> 1, wc = wid & 1;
  const long bm = (long)blockIdx.y * 128;
  const long bn = (long)blockIdx.x * 128;

  const int srow = wid * 32 + (lane >> 3);
  const int scol = (lane & 7) * 8;
  const u16* Ag = A + (bm + srow) * (long)lda + scol;
  const u16* Bg = B + (bn + srow) * (long)ldb + scol;
  u16* AsW = &As[wid * 32 * 64];
  u16* BsW = &Bs[wid * 32 * 64];

  f32x4 acc[4][4] = {};

  for (int k0 = 0; k0 < K; k0 += 64) {
    __syncthreads();
#pragma unroll
    for (int ch = 0; ch < 4; ++ch) {
      __builtin_amdgcn_global_load_lds((const GLV*)(Ag + (long)ch * 8 * lda + k0),
                                       (LDSV*)(AsW + ch * 512), 16, 0, 0);
      __builtin_amdgcn_global_load_lds((const GLV*)(Bg + (long)ch * 8 * ldb + k0),
                                       (LDSV*)(BsW + ch * 512), 16, 0, 0);
    }
    __syncthreads();
#pragma unroll
    for (int kk = 0; kk < 2; ++kk) {
      bf16x8 af[4], bfr[4];
#pragma unroll
      for (int m = 0; m < 4; ++m)
        af[m] = *(const bf16x8*)(&As[(wr * 64 + m * 16 + l15) * 64 + (kk * 4 + l4) * 8]);
#pragma unroll
      for (int n = 0; n < 4; ++n)
        bfr[n] = *(const bf16x8*)(&Bs[(wc * 64 + n * 16 + l15) * 64 + (kk * 4 + l4) * 8]);
#pragma unroll
      for (int m = 0; m < 4; ++m)
#pragma unroll
        for (int n = 0; n < 4; ++n)
          acc[m][n] = __builtin_amdgcn_mfma_f32_16x16x32_bf16(af[m], bfr[n], acc[m][n], 0, 0, 0);
    }
  }
#pragma unroll
  for (int m = 0; m < 4; ++m)
#pragma unroll
    for (int n = 0; n < 4; ++n)
#pragma unroll
      for (int r = 0; r < 4; ++r) {
        long row = bm + wr * 64 + m * 16 + l4 * 4 + r;
        long col = bn + wc * 64 + n * 16 + l15;
        float v = acc[m][n][r];
        if constexpr (MODE == 0) {
          ((u16*)Cv)[row * ldc + col] = f2bf(v);
        } else if constexpr (MODE == 1) {
          ((float*)Cv)[row * ldc + col] = v;
        } else {
          int h = (int)(col >> 8), c = (int)(col & 255);
          if (c < 128)  // k_nope -> Kb [bh][s][192]
            ((u16*)Cv)[(((row >> 11) * 16 + h) * 2048 + (row & 2047)) * 192 + c] = f2bf(v);
          else          // v -> Vc [b*S][h*128+d]
            Vc[row * 2048 + h * 128 + (c - 128)] = f2bf(v);
        }
      }
}

// ---------------- RMSNorm, in-place, one block per row ----------------
template <int NCH>
__global__ __launch_bounds__(256) void rmsnorm_kernel(u16* __restrict__ buf,
                                                      const float* __restrict__ w,
                                                      int stride, float oscale) {
  const int tid = threadIdx.x;
  u16* p = buf + (size_t)blockIdx.x * stride;
  float x[NCH];
  float ss = 0.f;
#pragma unroll
  for (int i = 0; i < NCH; ++i) { x[i] = bf2f(p[tid + i * 256]); ss += x[i] * x[i]; }
#pragma unroll
  for (int off = 1; off < 64; off <<= 1) ss += __shfl_xor(ss, off);
  __shared__ float sred[4];
  if ((tid & 63) == 0) sred[tid >> 6] = ss;
  __syncthreads();
  float tot = sred[0] + sred[1] + sred[2] + sred[3];
  float rs = rsqrtf(tot / (float)(NCH * 256) + 1e-6f) * oscale;
#pragma unroll
  for (int i = 0; i < NCH; ++i) p[tid + i * 256] = f2bf(x[i] * rs * w[tid + i * 256]);
}

// ---------------- RoPE on q_pe (in-place on q [4096][3072]) ----------------
__global__ __launch_bounds__(256) void rope_q_kernel(u16* __restrict__ q,
                                                     const float* __restrict__ cosb,
                                                     const float* __restrict__ sinb,
                                                     const float* __restrict__ gain) {
  int idx = blockIdx.x * 256 + threadIdx.x;  // B*S*H*32 = 2097152
  int i = idx & 31;
  int h = (idx >> 5) & 15;
  int srow = idx >> 9;
  int s = srow & (S_LEN - 1);
  size_t base = (size_t)srow * 3072 + h * 192 + 128 + 2 * i;
  unsigned int* p = (unsigned int*)(q + base);
  unsigned int v = *p;
  float xe = bf2f((u16)(v & 0xffff)), xo = bf2f((u16)(v >> 16));
  float c = cosb[s * 32 + i], sn = sinb[s * 32 + i];
  float g = gain[h];
  float ye = (xe * c - xo * sn) * g, yo = (xe * sn + xo * c) * g;
  *p = (unsigned int)f2bf(ye) | ((unsigned int)f2bf(yo) << 16);
}

// ---------------- RoPE on k_pe (in-place on qakv [4096][1408], cols 1280..1344) ----
__global__ __launch_bounds__(256) void rope_k_kernel(u16* __restrict__ kv,
                                                     const float* __restrict__ cosb,
                                                     const float* __restrict__ sinb) {
  int idx = blockIdx.x * 256 + threadIdx.x;  // 4096*32 = 131072
  int i = idx & 31;
  int srow = idx >> 5;
  int s = srow & (S_LEN - 1);
  size_t base = (size_t)srow * 1408 + 1280 + 2 * i;
  unsigned int* p = (unsigned int*)(kv + base);
  unsigned int v = *p;
  float xe = bf2f((u16)(v & 0xffff)), xo = bf2f((u16)(v >> 16));
  float c = cosb[s * 32 + i], sn = sinb[s * 32 + i];
  *p = (unsigned int)f2bf(xe * c - xo * sn) | ((unsigned int)f2bf(xe * sn + xo * c) << 16);
}

// ---------------- broadcast k_pe into Kb cols 128..192 ----------------
__global__ __launch_bounds__(256) void kpe_bcast_kernel(const u16* __restrict__ qakv,
                                                        u16* __restrict__ Kb) {
  int idx = blockIdx.x * 256 + threadIdx.x;  // 32bh*2048*8 = 524288
  int c8 = idx & 7;
  int rowid = idx >> 3;                // bh*2048 + s
  int bh = rowid >> 11, s = rowid & 2047;
  int b = bh >> 4;
  u32x4 v = *(const u32x4*)(qakv + ((long)b * 2048 + s) * 1408 + 1280 + c8 * 8);
  *(u32x4*)(Kb + (long)rowid * 192 + 128 + c8 * 8) = v;
}

// ---------------- V transpose: VT [B*H][128][S] from Vc [B*S][2048] ----------------
__global__ __launch_bounds__(256) void v_transpose_kernel(const u16* __restrict__ Vc,
                                                          u16* __restrict__ VT) {
  __shared__ u16 tile[32][33];
  int bh = blockIdx.z;
  int d0 = blockIdx.y * 32;
  int t0 = blockIdx.x * 32;
  int b = bh >> 4, h = bh & 15;
  int tx = threadIdx.x & 31, ty = threadIdx.x >> 5;
#pragma unroll
  for (int j = 0; j < 4; ++j) {
    int t = ty + j * 8;
    tile[t][tx] = Vc[((long)b * S_LEN + t0 + t) * 2048 + h * 128 + d0 + tx];
  }
  __syncthreads();
#pragma unroll
  for (int j = 0; j < 4; ++j) {
    int d = ty + j * 8;
    VT[((long)bh * 128 + d0 + d) * S_LEN + t0 + tx] = tile[tx][d];
  }
}

// ---------------- fused causal attention + softcap + v-projection removal ----------
// 8 waves, QT=128 (16 q-rows/wave), KT=64. Fixed softmax ref m=30. Paired q-tiles
// (qt,15-qt): 34 k-tiles per block uniformly. XCD swizzle: all 8 blocks of a bh on
// one XCD. Q pre-scaled by SCALE*log2(e)/15 in rmsnorm.
__global__ __launch_bounds__(512, 2) void attn_kernel(const u16* __restrict__ Qg,
                                                      const u16* __restrict__ Kg,
                                                      const u16* __restrict__ VTg,
                                                      const u16* __restrict__ Vcg,
                                                      u16* __restrict__ Yg) {
  __shared__ u16 Ks[64 * 192];    // 24KB
  __shared__ u16 VTs[128 * 64];   // 16KB
  __shared__ u16 Ps[128 * 64];    // 16KB

  const int tid = threadIdx.x, lane = tid & 63, wid = tid >> 6;
  const int l15 = lane & 15, l4 = lane >> 4;

  const int p = blockIdx.x;               // 256 blocks
  const int bh = (p & 7) * 4 + (p >> 6);  // same-bh blocks share an XCD
  const int pair = (p >> 3) & 7;
  const int b = bh >> 4, h = bh & 15;

  const u16* Kbh = Kg + (long)bh * S_LEN * 192;
  const u16* Vbh = VTg + (long)bh * 128 * S_LEN;

  int krow[3], kc[3], vrow[2], vc[2];
  u16* ksw[3]; u16* vsw[2];
#pragma unroll
  for (int i = 0; i < 3; ++i) {
    int flat = i * 512 + tid;
    krow[i] = flat / 24; kc[i] = flat % 24;
    ksw[i] = &Ks[krow[i] * 192 + ((kc[i] ^ (krow[i] & 7)) * 8)];
  }
#pragma unroll
  for (int i = 0; i < 2; ++i) {
    int flat = i * 512 + tid;
    vrow[i] = flat >> 3; vc[i] = flat & 7;
    vsw[i] = &VTs[vrow[i] * 64 + ((vc[i] ^ (vrow[i] & 7)) * 8)];
  }

  for (int seg = 0; seg < 2; ++seg) {
    const int qt = seg ? pair : 15 - pair;
    const int q0 = qt * 128;
    const int nkt = 2 * qt + 2;

    bf16x8 qf[6];
    {
      const u16* qb_ = Qg + ((long)b * S_LEN + q0 + wid * 16 + l15) * 3072 + h * 192;
#pragma unroll
      for (int f = 0; f < 6; ++f) qf[f] = *(const bf16x8*)(qb_ + f * 32 + 8 * l4);
    }

    f32x4 o[8] = {};
    float lsum[4] = {0.f, 0.f, 0.f, 0.f};

    u32x4 ka[3], va[2];
#pragma unroll
    for (int i = 0; i < 3; ++i)
      ka[i] = *(const u32x4*)(Kbh + (long)krow[i] * 192 + kc[i] * 8);
#pragma unroll
    for (int i = 0; i < 2; ++i)
      va[i] = *(const u32x4*)(Vbh + (long)vrow[i] * S_LEN + vc[i] * 8);

    for (int it = 0; it < nkt; ++it) {
      __syncthreads();
#pragma unroll
      for (int i = 0; i < 3; ++i) *(u32x4*)ksw[i] = ka[i];
#pragma unroll
      for (int i = 0; i < 2; ++i) *(u32x4*)vsw[i] = va[i];
      __syncthreads();
      if (it + 1 < nkt) {
        int k0n = (it + 1) * 64;
#pragma unroll
        for (int i = 0; i < 3; ++i)
          ka[i] = *(const u32x4*)(Kbh + (long)(k0n + krow[i]) * 192 + kc[i] * 8);
#pragma unroll
        for (int i = 0; i < 2; ++i)
          va[i] = *(const u32x4*)(Vbh + (long)vrow[i] * S_LEN + k0n + vc[i] * 8);
      }

      f32x4 sacc[4] = {};
      __builtin_amdgcn_s_setprio(1);
#pragma unroll
      for (int f = 0; f < 6; ++f)
#pragma unroll
        for (int tf = 0; tf < 4; ++tf) {
          int row = tf * 16 + l15;
          bf16x8 kf = *(const bf16x8*)(&Ks[row * 192 + (((f * 4 + l4) ^ (row & 7)) * 8)]);
          sacc[tf] = __builtin_amdgcn_mfma_f32_16x16x32_bf16(qf[f], kf, sacc[tf], 0, 0, 0);
        }
      __builtin_amdgcn_s_setprio(0);

      const bool diag = (it * 64 >= q0);
#pragma unroll
      for (int tf = 0; tf < 4; ++tf)
#pragma unroll
        for (int r = 0; r < 4; ++r) {
          // scores pre-scaled: p = exp2(-60*log2e / (exp2(s)+1))
          float u = __builtin_amdgcn_exp2f(sacc[tf][r]);
          float pe = __builtin_amdgcn_exp2f(-86.56170245333781f *
                                            __builtin_amdgcn_rcpf(u + 1.0f));
          if (diag && (it * 64 + tf * 16 + l15 > q0 + wid * 16 + l4 * 4 + r)) pe = 0.f;
          lsum[r] += pe;
          int prow = wid * 16 + l4 * 4 + r, col = tf * 16 + l15;
          Ps[prow * 64 + (((col >> 3) ^ (prow & 7)) * 8) + (col & 7)] = f2bf(pe);
        }

      __builtin_amdgcn_s_setprio(1);
      const int prow2 = wid * 16 + l15;
#pragma unroll
      for (int kk = 0; kk < 2; ++kk) {
        bf16x8 pf = *(const bf16x8*)(&Ps[prow2 * 64 + (((kk * 4 + l4) ^ (prow2 & 7)) * 8)]);
#pragma unroll
        for (int nf = 0; nf < 8; ++nf) {
          int vr = nf * 16 + l15;
          bf16x8 vf = *(const bf16x8*)(&VTs[vr * 64 + (((kk * 4 + l4) ^ (vr & 7)) * 8)]);
          o[nf] = __builtin_amdgcn_mfma_f32_16x16x32_bf16(pf, vf, o[nf], 0, 0, 0);
        }
      }
      __builtin_amdgcn_s_setprio(0);
    }

    float inv[4];
#pragma unroll
    for (int r = 0; r < 4; ++r) {
      float s = lsum[r];
      s += __shfl_xor(s, 1); s += __shfl_xor(s, 2);
      s += __shfl_xor(s, 4); s += __shfl_xor(s, 8);
      inv[r] = __builtin_amdgcn_rcpf(s);
    }

    // fused v-projection removal: y -= (y.v / max(|v|^2,eps)) v
    float yv[8][4], vvv[8][4];
    float ssum[4] = {0.f, 0.f, 0.f, 0.f}, dsum[4] = {0.f, 0.f, 0.f, 0.f};
    const u16* vb = Vcg + ((long)b * S_LEN + q0 + wid * 16) * 2048 + h * 128;
#pragma unroll
    for (int nf = 0; nf < 8; ++nf)
#pragma unroll
      for (int r = 0; r < 4; ++r) {
        float vv = bf2f(vb[(l4 * 4 + r) * 2048 + nf * 16 + l15]);
        float y = o[nf][r] * inv[r];
        vvv[nf][r] = vv; yv[nf][r] = y;
        ssum[r] += vv * vv; dsum[r] += y * vv;
      }
#pragma unroll
    for (int r = 0; r < 4; ++r) {
      ssum[r] += __shfl_xor(ssum[r], 1); ssum[r] += __shfl_xor(ssum[r], 2);
      ssum[r] += __shfl_xor(ssum[r], 4); ssum[r] += __shfl_xor(ssum[r], 8);
      dsum[r] += __shfl_xor(dsum[r], 1); dsum[r] += __shfl_xor(dsum[r], 2);
      dsum[r] += __shfl_xor(dsum[r], 4); dsum[r] += __shfl_xor(dsum[r], 8);
      dsum[r] *= __builtin_amdgcn_rcpf(fmaxf(ssum[r], 1e-12f));
    }
#pragma unroll
    for (int nf = 0; nf < 8; ++nf)
#pragma unroll
      for (int r = 0; r < 4; ++r) {
        long row = (long)b * S_LEN + q0 + wid * 16 + l4 * 4 + r;
        Yg[row * 2048 + h * 128 + nf * 16 + l15] = f2bf(yv[nf][r] - dsum[r] * vvv[nf][r]);
      }
  }
}

extern "C" void kernel_launch(void* const* d_in, const int* in_sizes, int n_in,
                              void* d_out, int out_size, void* d_ws, size_t ws_size,
                              hipStream_t stream) {
  const float* x       = (const float*)d_in[0];
  const float* wq_a    = (const float*)d_in[1];
  const float* q_norm  = (const float*)d_in[2];
  const float* wq_b    = (const float*)d_in[3];
  const float* q_gain  = (const float*)d_in[4];
  const float* wkv_a   = (const float*)d_in[5];
  const float* kv_norm = (const float*)d_in[6];
  const float* wkv_b   = (const float*)d_in[7];
  const float* wo      = (const float*)d_in[8];
  const float* fcos    = (const float*)d_in[9];
  const float* fsin    = (const float*)d_in[10];
  float* out = (float*)d_out;

  char* ws = (char*)d_ws;
  size_t off = 0;
  auto alloc = [&](size_t bytes) {
    char* pp = ws + off;
    off += (bytes + 255) & ~(size_t)255;
    return pp;
  };
  const long M = 4096;  // B*S
  u16* xb    = (u16*)alloc(M * 2048 * 2);
  u16* wcomb = (u16*)alloc(1408L * 2048 * 2);  // [wq_a(768); wkv_a(576)+pad(64)]
  u16* wqbb  = (u16*)alloc(3072L * 768 * 2);
  u16* wkvbb = (u16*)alloc(4096L * 512 * 2);
  u16* wob   = (u16*)alloc(2048L * 2048 * 2);
  u16* qakv  = (u16*)alloc(M * 1408 * 2);      // [qa(768) | kv(512) | kpe(64) | pad(64)]
  u16* qb    = (u16*)alloc(M * 3072 * 2);
  u16* Kb    = (u16*)alloc(32L * 2048 * 192 * 2);
  u16* Vc    = (u16*)alloc(M * 2048 * 2);
  u16* VTb   = (u16*)alloc(32L * 128 * 2048 * 2);
  u16* Yb    = (u16*)alloc(M * 2048 * 2);

  auto cast = [&](const float* s, u16* d, long n) {
    long n4 = n / 4;
    cast_f32_bf16<<<(n4 + 255) / 256, 256, 0, stream>>>(s, d, n4);
  };
  cast(x, xb, M * 2048);
  cast(wq_a, wcomb, 768L * 2048);
  {
    long n4 = 640L * 2048 / 4;
    cast_pad<<<(n4 + 255) / 256, 256, 0, stream>>>(wkv_a, wcomb + 768L * 2048, 576, n4, 2048);
  }
  cast(wq_b, wqbb, 3072L * 768);
  cast(wkv_b, wkvbb, 4096L * 512);
  cast(wo, wob, 2048L * 2048);

  // fused: [q_a | kv_full] = x @ [wq_a; wkv_a]^T   (N=1408)
  gemm_nt<0><<<dim3(11, 32), 256, 0, stream>>>(xb, 2048, wcomb, 2048, qakv, 1408, nullptr, 2048);
  // rmsnorm q_a, folding softcap/scale constant  SCALE*log2(e)/15
  rmsnorm_kernel<3><<<4096, 256, 0, stream>>>(qakv, q_norm, 1408, 0.0069411711f);
  rmsnorm_kernel<2><<<4096, 256, 0, stream>>>(qakv + 768, kv_norm, 1408, 1.0f);
  // q = q_a @ wq_b^T
  gemm_nt<0><<<dim3(24, 32), 256, 0, stream>>>(qakv, 1408, wqbb, 768, qb, 3072, nullptr, 768);
  rope_q_kernel<<<2097152 / 256, 256, 0, stream>>>(qb, fcos, fsin, q_gain);
  rope_k_kernel<<<131072 / 256, 256, 0, stream>>>(qakv, fcos, fsin);
  // kvb = kv @ wkv_b^T, epilogue-split into Kb (k_nope) and Vc (v)
  gemm_nt<2><<<dim3(32, 32), 256, 0, stream>>>(qakv + 768, 1408, wkvbb, 512, Kb, 0, Vc, 512);
  kpe_bcast_kernel<<<524288 / 256, 256, 0, stream>>>(qakv, Kb);
  v_transpose_kernel<<<dim3(64, 4, 32), 256, 0, stream>>>(Vc, VTb);
  attn_kernel<<<256, 512, 0, stream>>>(qb, Kb, VTb, Vc, Yb);
  // out = y @ wo^T (f32 out)
  gemm_nt<1><<<dim3(16, 32), 256, 0, stream>>>(Yb, 2048, wob, 2048, out, 2048, nullptr, 2048);
}